// Round 1
// baseline (2022.515 us; speedup 1.0000x reference)
//
#include <hip/hip_runtime.h>
#include <math.h>

// Fused: y = tanh(tanh(min_k( conv3x3(x, w)[k] + b[k] )))
// x: [16,64,256,256] f32, w: [64,64,3,3] f32, b: [64] f32, out: [16,1,256,256] f32
//
// Block = 256 threads -> 16(H) x 64(W) output tile for one n.
// Thread owns 4 adjacent output pixels along W (register x-reuse).
// K chunked by KC=16 (acc[16][4] regs); x tile re-staged per k-chunk.
// LDS: sW 36.9KB (contiguous w chunk, broadcast reads) + sX 19.0KB = 55.9KB -> 2 blocks/CU.

#define TILE_H 16
#define TILE_W 64
#define PX 4
#define KC 16
#define CC 4
#define XW (TILE_W + 2)   // 66
#define XH (TILE_H + 2)   // 18

__global__ __launch_bounds__(256, 2)
void conv_min_tanh_kernel(const float* __restrict__ x,
                          const float* __restrict__ w,
                          const float* __restrict__ b,
                          float* __restrict__ out)
{
    __shared__ float sW[KC * 64 * 9];    // 9216 f = 36864 B
    __shared__ float sX[CC * XH * XW];   // 4752 f = 19008 B

    const int tid = threadIdx.x;
    const int py  = tid >> 4;            // 0..15
    const int qx  = (tid & 15) * PX;     // 0,4,...,60
    const int n   = blockIdx.z;
    const int h0  = blockIdx.y * TILE_H;
    const int w0  = blockIdx.x * TILE_W;

    float minv[PX];
#pragma unroll
    for (int j = 0; j < PX; ++j) minv[j] = 1e30f;

#pragma unroll 1
    for (int kc = 0; kc < 64; kc += KC) {
        __syncthreads();  // prior compute (reads sW) done before restage
        // stage w[kc..kc+KC) — contiguous 9216 floats, float4 copy
        {
            const float4* src = (const float4*)(w + kc * (64 * 9));
            float4* dst = (float4*)sW;
            for (int i = tid; i < (KC * 64 * 9) / 4; i += 256)
                dst[i] = src[i];
        }

        float acc[KC][PX];
#pragma unroll
        for (int k = 0; k < KC; ++k) {
            const float bk = b[kc + k];
#pragma unroll
            for (int j = 0; j < PX; ++j) acc[k][j] = bk;
        }

#pragma unroll 1
        for (int cc = 0; cc < 64; cc += CC) {
            __syncthreads();  // prior compute (reads sX) done before restage
            // stage x[cc..cc+CC), rows h0-1..h0+16, cols w0-1..w0+64 (zero pad)
            for (int i = tid; i < CC * XH * XW; i += 256) {
                const int c  = i / (XH * XW);
                const int rm = i - c * (XH * XW);
                const int hh = rm / XW;
                const int ww = rm - hh * XW;
                const int gh = h0 + hh - 1;
                const int gw = w0 + ww - 1;
                float v = 0.0f;
                if ((unsigned)gh < 256u && (unsigned)gw < 256u)
                    v = x[(((size_t)n * 64 + (cc + c)) * 256 + gh) * 256 + gw];
                sX[i] = v;
            }
            __syncthreads();  // staging (sX and, on cc==0, sW) visible

#pragma unroll
            for (int c = 0; c < CC; ++c) {
#pragma unroll
                for (int r = 0; r < 3; ++r) {
                    const float* xrow = &sX[(c * XH + py + r) * XW + qx];
                    float xr[PX + 2];
#pragma unroll
                    for (int t = 0; t < PX + 2; ++t) xr[t] = xrow[t];
                    const float* wp = &sW[(cc + c) * 9 + r * 3];
#pragma unroll
                    for (int k = 0; k < KC; ++k) {
                        const float w0v = wp[k * 576 + 0];
                        const float w1v = wp[k * 576 + 1];
                        const float w2v = wp[k * 576 + 2];
#pragma unroll
                        for (int j = 0; j < PX; ++j) {
                            acc[k][j] = fmaf(xr[j + 2], w2v,
                                        fmaf(xr[j + 1], w1v,
                                        fmaf(xr[j],     w0v, acc[k][j])));
                        }
                    }
                }
            }
        }

#pragma unroll
        for (int k = 0; k < KC; ++k)
#pragma unroll
            for (int j = 0; j < PX; ++j)
                minv[j] = fminf(minv[j], acc[k][j]);
    }

    const int p = h0 + py;
    float4 o;
    o.x = tanhf(tanhf(minv[0]));
    o.y = tanhf(tanhf(minv[1]));
    o.z = tanhf(tanhf(minv[2]));
    o.w = tanhf(tanhf(minv[3]));
    *(float4*)(out + ((size_t)n * 256 + p) * 256 + w0 + qx) = o;
}

extern "C" void kernel_launch(void* const* d_in, const int* in_sizes, int n_in,
                              void* d_out, int out_size, void* d_ws, size_t ws_size,
                              hipStream_t stream) {
    const float* x = (const float*)d_in[0];
    const float* w = (const float*)d_in[1];
    const float* b = (const float*)d_in[2];
    float* out = (float*)d_out;
    dim3 grid(256 / TILE_W, 256 / TILE_H, 16);  // (4, 16, 16)
    conv_min_tanh_kernel<<<grid, dim3(256), 0, stream>>>(x, w, b, out);
}

// Round 2
// 636.702 us; speedup vs baseline: 3.1766x; 3.1766x over previous
//
#include <hip/hip_runtime.h>
#include <hip/hip_bf16.h>
#include <math.h>

// Fused conv3x3(64->64) + bias + min_k + tanh(tanh()) via bf16 MFMA implicit GEMM.
// x: [16,64,256,256] f32, w: [64,64,3,3] f32, b: [64] f32, out: [16,1,256,256] f32
//
// mfma_f32_16x16x32_bf16: A[m=lane&15][k=(lane>>4)*8+j], B[k][n=lane&15],
//                         C/D col=lane&15, row=(lane>>4)*4+reg  (HW-verified layouts)
// M = pixels (16-wide row segments), N = 64 output channels (4 n-tiles, min in-wave),
// reduction = c(64) x taps(9) = 2 chunks x 9 taps of K=32.
//
// WG = 256 thr = 4 waves; WG tile 16(H)x16(W); wave w owns rows 4w..4w+3 (4 m-tiles)
// x all 4 n-tiles. acc = 4x4 f32x4 = 64 VGPR.
// sX: [q(4)][row(18)][col(18)][j(8)] bf16 = 20736 B, 16B slots -> aligned ds_read_b128.
// Weights pre-converted to bf16 B-layout in d_ws: [chunk(2)][tap(9)][k(64)][c'(32)]
// -> B-frag = coalesced global dwordx4 (wave reads contiguous 1KB), no LDS for B.

typedef __bf16 bf16x8 __attribute__((ext_vector_type(8)));
typedef float f32x4 __attribute__((ext_vector_type(4)));

#define TH 16
#define TW 16
#define SROW 18
#define SCOL 18

__global__ __launch_bounds__(256)
void conv_prep_w(const float* __restrict__ w, __bf16* __restrict__ wB) {
    int idx = blockIdx.x * 256 + threadIdx.x;
    if (idx >= 64 * 64 * 9) return;
    int k   = idx / 576;
    int rem = idx - k * 576;
    int c   = rem / 9;
    int tap = rem - c * 9;
    // [chunk][tap][k][c']
    wB[((((c >> 5) * 9 + tap) * 64 + k) * 32) + (c & 31)] = (__bf16)w[idx];
}

__global__ __launch_bounds__(256, 2)
void conv_min_tanh_mfma(const float* __restrict__ x,
                        const __bf16* __restrict__ wB,
                        const float* __restrict__ b,
                        float* __restrict__ out)
{
    __shared__ __attribute__((aligned(16))) __bf16 sX[4 * SROW * SCOL * 8];

    const int tid  = threadIdx.x;
    const int lane = tid & 63;
    const int wave = tid >> 6;
    const int n    = blockIdx.z;
    const int h0   = blockIdx.y * TH;
    const int w0   = blockIdx.x * TW;
    const int m15  = lane & 15;
    const int q    = lane >> 4;

    f32x4 acc[4][4];  // [mt][nt]
#pragma unroll
    for (int mt = 0; mt < 4; ++mt)
#pragma unroll
        for (int nt = 0; nt < 4; ++nt)
            acc[mt][nt] = (f32x4){0.f, 0.f, 0.f, 0.f};

#pragma unroll 1
    for (int chunk = 0; chunk < 2; ++chunk) {
        __syncthreads();  // prior compute reads of sX done
        // ---- stage x[c=chunk*32..+32), rows h0-1..h0+16, cols w0-1..w0+16 ----
        const float* xc = x + (size_t)(n * 64 + chunk * 32) * 65536;
        for (int i = tid; i < 32 * SROW * SCOL; i += 256) {
            int cl  = i / (SROW * SCOL);
            int rem = i - cl * (SROW * SCOL);
            int row = rem / SCOL;
            int col = rem - row * SCOL;
            int gh = h0 + row - 1;
            int gw = w0 + col - 1;
            float v = 0.f;
            if ((unsigned)gh < 256u && (unsigned)gw < 256u)
                v = xc[(size_t)cl * 65536 + gh * 256 + gw];
            sX[(((cl >> 3) * (SROW * SCOL) + row * SCOL + col) << 3) + (cl & 7)] = (__bf16)v;
        }
        __syncthreads();

        const __bf16* wBc = wB + chunk * (9 * 64 * 32);
#pragma unroll
        for (int tap = 0; tap < 9; ++tap) {
            const int r = tap / 3;
            const int s = tap - r * 3;
            bf16x8 bf[4];
#pragma unroll
            for (int nt = 0; nt < 4; ++nt)
                bf[nt] = *(const bf16x8*)&wBc[((tap * 64 + nt * 16 + m15) << 5) + (q << 3)];
#pragma unroll
            for (int mt = 0; mt < 4; ++mt) {
                const int rowg = wave * 4 + mt + r;  // sX row (halo-offset included)
                const int colg = m15 + s;            // sX col
                bf16x8 af = *(const bf16x8*)&sX[((q * (SROW * SCOL) + rowg * SCOL + colg) << 3)];
#pragma unroll
                for (int nt = 0; nt < 4; ++nt)
                    acc[mt][nt] = __builtin_amdgcn_mfma_f32_16x16x32_bf16(af, bf[nt], acc[mt][nt], 0, 0, 0);
            }
        }
    }

    // ---- epilogue: +bias, min over 64 k, tanh(tanh), store ----
    float bias[4];
#pragma unroll
    for (int nt = 0; nt < 4; ++nt) bias[nt] = b[nt * 16 + m15];

#pragma unroll
    for (int mt = 0; mt < 4; ++mt) {
        float mv[4];
#pragma unroll
        for (int reg = 0; reg < 4; ++reg) {
            float v = acc[mt][0][reg] + bias[0];
            v = fminf(v, acc[mt][1][reg] + bias[1]);
            v = fminf(v, acc[mt][2][reg] + bias[2]);
            v = fminf(v, acc[mt][3][reg] + bias[3]);
            // min across the 16 lanes of the quad (16 n-values per tile)
            v = fminf(v, __shfl_xor(v, 1));
            v = fminf(v, __shfl_xor(v, 2));
            v = fminf(v, __shfl_xor(v, 4));
            v = fminf(v, __shfl_xor(v, 8));
            mv[reg] = v;  // all 16 lanes of quad now hold min for row = q*4+reg
        }
        const int r2 = lane & 3;
        float v = mv[0];
        v = (r2 == 1) ? mv[1] : v;
        v = (r2 == 2) ? mv[2] : v;
        v = (r2 == 3) ? mv[3] : v;
        v = tanhf(tanhf(v));
        if (m15 < 4) {
            const int pix = q * 4 + r2;          // D row = pixel col within tile
            const int gh  = h0 + wave * 4 + mt;
            const int gw  = w0 + pix;
            out[((size_t)n * 256 + gh) * 256 + gw] = v;
        }
    }
}

extern "C" void kernel_launch(void* const* d_in, const int* in_sizes, int n_in,
                              void* d_out, int out_size, void* d_ws, size_t ws_size,
                              hipStream_t stream) {
    const float* x = (const float*)d_in[0];
    const float* w = (const float*)d_in[1];
    const float* b = (const float*)d_in[2];
    float* out = (float*)d_out;
    __bf16* wB = (__bf16*)d_ws;  // needs 64*64*9*2 = 73728 B

    conv_prep_w<<<dim3(144), dim3(256), 0, stream>>>(w, wB);
    conv_min_tanh_mfma<<<dim3(256 / TW, 256 / TH, 16), dim3(256), 0, stream>>>(x, wB, b, out);
}

// Round 3
// 634.702 us; speedup vs baseline: 3.1866x; 1.0032x over previous
//
#include <hip/hip_runtime.h>
#include <hip/hip_bf16.h>
#include <math.h>

// Fused conv3x3(64->64) + bias + min_k + tanh(tanh()) via bf16 MFMA implicit GEMM.
// x: [16,64,256,256] f32, w: [64,64,3,3] f32, b: [64] f32, out: [16,1,256,256] f32
//
// Round 3: transpose moved OUT of the hot kernel.
//   prep_x: NCHW fp32 -> zero-padded NHWC bf16 xP[16][258][258][64] in d_ws (130 MB).
//   main  : no LDS, no barriers. A-frags = coalesced global dwordx4 (8 contig c per
//           lane), B-frags = coalesced global dwordx4 from prepped weights. L1-fed.
// mfma_f32_16x16x32_bf16: A[m=lane&15][k=(lane>>4)*8+j], B[k][n=lane&15],
//                         C/D col=lane&15, row=(lane>>4)*4+reg (HW-verified).

typedef __bf16 bf16x8 __attribute__((ext_vector_type(8)));
typedef float f32x4 __attribute__((ext_vector_type(4)));

#define WB_ELEMS (64 * 64 * 9)
#define WB_BYTES (WB_ELEMS * 2)                       // 73728
#define XP_BYTES (16ull * 258 * 258 * 64 * 2)         // 136323072
#define WS_NEEDED (WB_BYTES + XP_BYTES)

// ---------------- weight prep: [chunk(2)][tap(9)][k(64)][c'(32)] bf16 ----------------
__global__ __launch_bounds__(256)
void conv_prep_w(const float* __restrict__ w, __bf16* __restrict__ wB) {
    int idx = blockIdx.x * 256 + threadIdx.x;
    if (idx >= WB_ELEMS) return;
    int k   = idx / 576;
    int rem = idx - k * 576;
    int c   = rem / 9;
    int tap = rem - c * 9;
    wB[((((c >> 5) * 9 + tap) * 64 + k) * 32) + (c & 31)] = (__bf16)w[idx];
}

// ---------------- x prep: NCHW fp32 -> padded NHWC bf16 [16][258][258][64] ----------------
__global__ __launch_bounds__(256)
void conv_prep_x(const float* __restrict__ x, __bf16* __restrict__ xP) {
    const int n  = blockIdx.y;
    const int hp = blockIdx.x;          // 0..257
    const int gh = hp - 1;
    for (int wp = threadIdx.x; wp < 258; wp += 256) {
        const int gw = wp - 1;
        bf16x8* dst = (bf16x8*)(xP + ((size_t)(n * 258 + hp) * 258 + wp) * 64);
        if ((unsigned)gh < 256u && (unsigned)gw < 256u) {
            const float* src = x + (size_t)n * 64 * 65536 + (size_t)gh * 256 + gw;
#pragma unroll
            for (int cg = 0; cg < 8; ++cg) {
                bf16x8 t;
#pragma unroll
                for (int j = 0; j < 8; ++j)
                    t[j] = (__bf16)src[(size_t)(cg * 8 + j) * 65536];
                dst[cg] = t;
            }
        } else {
            bf16x8 z = (bf16x8)(__bf16)0.f;
#pragma unroll
            for (int cg = 0; cg < 8; ++cg) dst[cg] = z;
        }
    }
}

// ---------------- main: LDS-free, barrier-free MFMA stream ----------------
__global__ __launch_bounds__(256, 4)
void conv_min_tanh_main(const __bf16* __restrict__ xP,
                        const __bf16* __restrict__ wB,
                        const float* __restrict__ b,
                        float* __restrict__ out)
{
    const int tid  = threadIdx.x;
    const int lane = tid & 63;
    const int wave = tid >> 6;
    const int n    = blockIdx.z;
    const int h0   = blockIdx.y * 16;
    const int w0   = blockIdx.x * 16;
    const int m15  = lane & 15;
    const int q    = lane >> 4;

    f32x4 acc[4][4];  // [mt][nt]
#pragma unroll
    for (int mt = 0; mt < 4; ++mt)
#pragma unroll
        for (int nt = 0; nt < 4; ++nt)
            acc[mt][nt] = (f32x4){0.f, 0.f, 0.f, 0.f};

    const size_t rowStride = 258 * 64;

#pragma unroll 1
    for (int chunk = 0; chunk < 2; ++chunk) {
        // lane base: image n, padded row h0+4*wave, padded col w0+m15, c = chunk*32+q*8
        const __bf16* xb = xP + ((size_t)(n * 258 + h0 + 4 * wave) * 258 + (w0 + m15)) * 64
                              + chunk * 32 + q * 8;
        const __bf16* wBc = wB + chunk * (9 * 64 * 32);
#pragma unroll
        for (int r = 0; r < 3; ++r) {
#pragma unroll
            for (int s = 0; s < 3; ++s) {
                const int tap = r * 3 + s;
                bf16x8 bf[4];
#pragma unroll
                for (int nt = 0; nt < 4; ++nt)
                    bf[nt] = *(const bf16x8*)&wBc[((tap * 64 + nt * 16 + m15) << 5) + (q << 3)];
#pragma unroll
                for (int mt = 0; mt < 4; ++mt) {
                    bf16x8 af = *(const bf16x8*)&xb[(size_t)(mt + r) * rowStride + (size_t)s * 64];
#pragma unroll
                    for (int nt = 0; nt < 4; ++nt)
                        acc[mt][nt] = __builtin_amdgcn_mfma_f32_16x16x32_bf16(af, bf[nt], acc[mt][nt], 0, 0, 0);
                }
            }
        }
    }

    // ---- epilogue: +bias, min over 64 k, tanh(tanh), store (verified round 2) ----
    float bias[4];
#pragma unroll
    for (int nt = 0; nt < 4; ++nt) bias[nt] = b[nt * 16 + m15];

#pragma unroll
    for (int mt = 0; mt < 4; ++mt) {
        float mv[4];
#pragma unroll
        for (int reg = 0; reg < 4; ++reg) {
            float v = acc[mt][0][reg] + bias[0];
            v = fminf(v, acc[mt][1][reg] + bias[1]);
            v = fminf(v, acc[mt][2][reg] + bias[2]);
            v = fminf(v, acc[mt][3][reg] + bias[3]);
            v = fminf(v, __shfl_xor(v, 1));
            v = fminf(v, __shfl_xor(v, 2));
            v = fminf(v, __shfl_xor(v, 4));
            v = fminf(v, __shfl_xor(v, 8));
            mv[reg] = v;
        }
        const int r2 = lane & 3;
        float v = mv[0];
        v = (r2 == 1) ? mv[1] : v;
        v = (r2 == 2) ? mv[2] : v;
        v = (r2 == 3) ? mv[3] : v;
        v = tanhf(tanhf(v));
        if (m15 < 4) {
            const int pix = q * 4 + r2;
            const int gh  = h0 + wave * 4 + mt;
            const int gw  = w0 + pix;
            out[((size_t)n * 256 + gh) * 256 + gw] = v;
        }
    }
}

// ---------------- fallback (round-2 kernel, used only if ws too small) ----------------
#define TH 16
#define TW 16
#define SROW 18
#define SCOL 18

__global__ __launch_bounds__(256, 2)
void conv_min_tanh_fb(const float* __restrict__ x,
                      const __bf16* __restrict__ wB,
                      const float* __restrict__ b,
                      float* __restrict__ out)
{
    __shared__ __attribute__((aligned(16))) __bf16 sX[4 * SROW * SCOL * 8];
    const int tid = threadIdx.x;
    const int lane = tid & 63;
    const int wave = tid >> 6;
    const int n = blockIdx.z;
    const int h0 = blockIdx.y * TH;
    const int w0 = blockIdx.x * TW;
    const int m15 = lane & 15;
    const int q = lane >> 4;

    f32x4 acc[4][4];
#pragma unroll
    for (int mt = 0; mt < 4; ++mt)
#pragma unroll
        for (int nt = 0; nt < 4; ++nt) acc[mt][nt] = (f32x4){0.f, 0.f, 0.f, 0.f};

#pragma unroll 1
    for (int chunk = 0; chunk < 2; ++chunk) {
        __syncthreads();
        const float* xc = x + (size_t)(n * 64 + chunk * 32) * 65536;
        for (int i = tid; i < 32 * SROW * SCOL; i += 256) {
            int cl = i / (SROW * SCOL);
            int rem = i - cl * (SROW * SCOL);
            int row = rem / SCOL;
            int col = rem - row * SCOL;
            int gh = h0 + row - 1;
            int gw = w0 + col - 1;
            float v = 0.f;
            if ((unsigned)gh < 256u && (unsigned)gw < 256u)
                v = xc[(size_t)cl * 65536 + gh * 256 + gw];
            sX[(((cl >> 3) * (SROW * SCOL) + row * SCOL + col) << 3) + (cl & 7)] = (__bf16)v;
        }
        __syncthreads();
        const __bf16* wBc = wB + chunk * (9 * 64 * 32);
#pragma unroll
        for (int tap = 0; tap < 9; ++tap) {
            const int r = tap / 3;
            const int s = tap - r * 3;
            bf16x8 bf[4];
#pragma unroll
            for (int nt = 0; nt < 4; ++nt)
                bf[nt] = *(const bf16x8*)&wBc[((tap * 64 + nt * 16 + m15) << 5) + (q << 3)];
#pragma unroll
            for (int mt = 0; mt < 4; ++mt) {
                const int rowg = wave * 4 + mt + r;
                const int colg = m15 + s;
                bf16x8 af = *(const bf16x8*)&sX[((q * (SROW * SCOL) + rowg * SCOL + colg) << 3)];
#pragma unroll
                for (int nt = 0; nt < 4; ++nt)
                    acc[mt][nt] = __builtin_amdgcn_mfma_f32_16x16x32_bf16(af, bf[nt], acc[mt][nt], 0, 0, 0);
            }
        }
    }
    float bias[4];
#pragma unroll
    for (int nt = 0; nt < 4; ++nt) bias[nt] = b[nt * 16 + m15];
#pragma unroll
    for (int mt = 0; mt < 4; ++mt) {
        float mv[4];
#pragma unroll
        for (int reg = 0; reg < 4; ++reg) {
            float v = acc[mt][0][reg] + bias[0];
            v = fminf(v, acc[mt][1][reg] + bias[1]);
            v = fminf(v, acc[mt][2][reg] + bias[2]);
            v = fminf(v, acc[mt][3][reg] + bias[3]);
            v = fminf(v, __shfl_xor(v, 1));
            v = fminf(v, __shfl_xor(v, 2));
            v = fminf(v, __shfl_xor(v, 4));
            v = fminf(v, __shfl_xor(v, 8));
            mv[reg] = v;
        }
        const int r2 = lane & 3;
        float v = mv[0];
        v = (r2 == 1) ? mv[1] : v;
        v = (r2 == 2) ? mv[2] : v;
        v = (r2 == 3) ? mv[3] : v;
        v = tanhf(tanhf(v));
        if (m15 < 4) {
            out[((size_t)n * 256 + h0 + wave * 4 + mt) * 256 + w0 + q * 4 + r2] = v;
        }
    }
}

extern "C" void kernel_launch(void* const* d_in, const int* in_sizes, int n_in,
                              void* d_out, int out_size, void* d_ws, size_t ws_size,
                              hipStream_t stream) {
    const float* x = (const float*)d_in[0];
    const float* w = (const float*)d_in[1];
    const float* b = (const float*)d_in[2];
    float* out = (float*)d_out;
    __bf16* wB = (__bf16*)d_ws;
    conv_prep_w<<<dim3(144), dim3(256), 0, stream>>>(w, wB);

    if (ws_size >= WS_NEEDED) {
        __bf16* xP = (__bf16*)((char*)d_ws + WB_BYTES);
        conv_prep_x<<<dim3(258, 16), dim3(256), 0, stream>>>(x, xP);
        conv_min_tanh_main<<<dim3(16, 16, 16), dim3(256), 0, stream>>>(xP, wB, b, out);
    } else {
        conv_min_tanh_fb<<<dim3(16, 16, 16), dim3(256), 0, stream>>>(x, wB, b, out);
    }
}

// Round 4
// 480.978 us; speedup vs baseline: 4.2050x; 1.3196x over previous
//
#include <hip/hip_runtime.h>
#include <hip/hip_bf16.h>
#include <math.h>

// Fused conv3x3(64->64) + bias + min_k + tanh(tanh()) via bf16 MFMA implicit GEMM.
// x: [16,64,256,256] f32, w: [64,64,3,3] f32, b: [64] f32, out: [16,1,256,256] f32
//
// Round 4:
//   prep_x : LDS-transpose NCHW f32 -> padded NHWC bf16 xP[16][258][258][64] (fully
//            coalesced float4 reads, contiguous bf16x8 writes). Border zeroed once.
//   prep_w : bf16 B-fragment DUMP layout [chunk(2)][tap(9)][nt(4)][lane(64)][j(8)]
//            -> lane-contiguous ds_read_b128, conflict-free.
//   main   : per chunk: stage 36KB B into LDS (once), burst-load 18 A-frags
//            (row 0..5 x s 0..2) into regs, then 9 taps x 16 MFMA fed entirely from
//            regs + LDS. Per-block L2 B-traffic 288KB -> 72KB; A L1-resident.
// mfma_f32_16x16x32_bf16: A[m=lane&15][k=(lane>>4)*8+j], B[k=(lane>>4)*8+j][n=lane&15],
//                         C/D col=lane&15, row=(lane>>4)*4+reg (HW-verified, r2/r3 pass).

typedef __bf16 bf16x8 __attribute__((ext_vector_type(8)));
typedef float f32x4 __attribute__((ext_vector_type(4)));

#define WB_ELEMS (64 * 64 * 9)
#define WB_BYTES (WB_ELEMS * 2)                    // 73728
#define XP_BYTES (16ull * 258 * 258 * 64 * 2)      // 136323072
#define WS_NEEDED (WB_BYTES + XP_BYTES)
#define ROWSTRIDE (258 * 64)                       // xP padded row stride (elements)

// ---- weight prep: value w[k][c][tap] -> wB[(((chunk*9+tap)*4+nt)*64+lane)*8+j]
//      with k = nt*16+m15, c = chunk*32+q*8+j, lane = (q<<4)|m15
__global__ __launch_bounds__(256)
void conv_prep_w(const float* __restrict__ w, __bf16* __restrict__ wB) {
    int idx = blockIdx.x * 256 + threadIdx.x;
    if (idx >= WB_ELEMS) return;
    int k   = idx / 576;
    int rem = idx - k * 576;
    int c   = rem / 9;
    int tap = rem - c * 9;
    int nt = k >> 4, m15 = k & 15;
    int chunk = c >> 5, q = (c >> 3) & 3, j = c & 7;
    int lane = (q << 4) | m15;
    wB[((((chunk * 9 + tap) * 4 + nt) * 64 + lane) << 3) + j] = (__bf16)w[idx];
}

// ---- zero the 1-pixel border of xP (rows/cols 0 and 257) ----
__global__ __launch_bounds__(256)
void conv_zero_border(__bf16* __restrict__ xP) {
    const int n = blockIdx.x, seg = blockIdx.y;
    const bf16x8 z = (bf16x8)(__bf16)0.f;
    for (int i = threadIdx.x; i < 258 * 8; i += 256) {
        int px = i >> 3, g = i & 7;
        int hp, wp;
        if      (seg == 0) { hp = 0;   wp = px; }
        else if (seg == 1) { hp = 257; wp = px; }
        else if (seg == 2) { hp = px;  wp = 0; }
        else               { hp = px;  wp = 257; }
        *(bf16x8*)&xP[((size_t)(n * 258 + hp) * 258 + wp) * 64 + g * 8] = z;
    }
}

// ---- x prep: LDS transpose. Block = 64 px (one row) x 64 c for one (n, hp). ----
__global__ __launch_bounds__(256)
void conv_prep_x(const float* __restrict__ x, __bf16* __restrict__ xP) {
    __shared__ __attribute__((aligned(16))) __bf16 sT[64][72];  // +8 pad, 16B-aligned rows
    const int tid = threadIdx.x;
    const int n = blockIdx.z;
    const int hp = blockIdx.y + 1;           // padded row 1..256
    const int wbase = blockIdx.x * 64;       // input cols wbase..wbase+63
    const float* src = x + (size_t)n * 64 * 65536 + (size_t)(hp - 1) * 256 + wbase;
#pragma unroll
    for (int i = 0; i < 4; ++i) {
        int idx = i * 256 + tid;
        int c = idx >> 4, f4 = idx & 15;     // 16 float4 per channel row
        float4 v = *(const float4*)&src[(size_t)c * 65536 + f4 * 4];
        sT[f4 * 4 + 0][c] = (__bf16)v.x;
        sT[f4 * 4 + 1][c] = (__bf16)v.y;
        sT[f4 * 4 + 2][c] = (__bf16)v.z;
        sT[f4 * 4 + 3][c] = (__bf16)v.w;
    }
    __syncthreads();
    __bf16* dstbase = xP + ((size_t)(n * 258 + hp) * 258 + (wbase + 1)) * 64;
#pragma unroll
    for (int i = 0; i < 2; ++i) {
        int idx = i * 256 + tid;
        int px = idx >> 3, g = idx & 7;
        *(bf16x8*)&dstbase[(size_t)px * 64 + g * 8] = *(const bf16x8*)&sT[px][g * 8];
    }
}

// ---- main: B in LDS, A in regs, MFMA stream ----
__global__ __launch_bounds__(256, 2)
void conv_min_tanh_main(const __bf16* __restrict__ xP,
                        const __bf16* __restrict__ wB,
                        const float* __restrict__ b,
                        float* __restrict__ out)
{
    __shared__ __attribute__((aligned(16))) __bf16 sB[9 * 4 * 64 * 8];  // 36 KB, one chunk

    const int tid  = threadIdx.x;
    const int lane = tid & 63;
    const int wave = tid >> 6;
    const int n    = blockIdx.z;
    const int h0   = blockIdx.y * 16;
    const int w0   = blockIdx.x * 16;
    const int m15  = lane & 15;
    const int q    = lane >> 4;

    f32x4 acc[4][4];  // [mt][nt]
#pragma unroll
    for (int mt = 0; mt < 4; ++mt)
#pragma unroll
        for (int nt = 0; nt < 4; ++nt)
            acc[mt][nt] = (f32x4){0.f, 0.f, 0.f, 0.f};

    // lane A base: padded row h0+4*wave, padded col w0+m15, channel q*8
    const __bf16* xbase = xP + ((size_t)(n * 258 + h0 + 4 * wave) * 258 + (w0 + m15)) * 64
                             + q * 8;

#pragma unroll 1
    for (int chunk = 0; chunk < 2; ++chunk) {
        if (chunk) __syncthreads();          // all reads of sB chunk 0 done
        {   // stage this chunk's 36 KB of B into LDS (contiguous copy)
            const float4* src = (const float4*)(wB + chunk * (9 * 4 * 64 * 8));
            float4* dst = (float4*)sB;
#pragma unroll
            for (int i = 0; i < 9; ++i)
                dst[i * 256 + tid] = src[i * 256 + tid];
        }
        __syncthreads();

        // burst-load the 18 A fragments for this chunk: rows 0..5, s 0..2
        bf16x8 af[6][3];
        const __bf16* xc = xbase + chunk * 32;
#pragma unroll
        for (int row = 0; row < 6; ++row)
#pragma unroll
            for (int s = 0; s < 3; ++s)
                af[row][s] = *(const bf16x8*)&xc[(size_t)row * ROWSTRIDE + s * 64];

#pragma unroll
        for (int r = 0; r < 3; ++r) {
#pragma unroll
            for (int s = 0; s < 3; ++s) {
                const int tap = r * 3 + s;
                bf16x8 bf[4];
#pragma unroll
                for (int nt = 0; nt < 4; ++nt)
                    bf[nt] = *(const bf16x8*)&sB[((tap * 4 + nt) * 64 + lane) << 3];
#pragma unroll
                for (int mt = 0; mt < 4; ++mt)
#pragma unroll
                    for (int nt = 0; nt < 4; ++nt)
                        acc[mt][nt] = __builtin_amdgcn_mfma_f32_16x16x32_bf16(
                            af[mt + r][s], bf[nt], acc[mt][nt], 0, 0, 0);
            }
        }
    }

    // ---- epilogue: +bias, min over 64 k, tanh(tanh), store (verified r2/r3) ----
    float bias[4];
#pragma unroll
    for (int nt = 0; nt < 4; ++nt) bias[nt] = b[nt * 16 + m15];

#pragma unroll
    for (int mt = 0; mt < 4; ++mt) {
        float mv[4];
#pragma unroll
        for (int reg = 0; reg < 4; ++reg) {
            float v = acc[mt][0][reg] + bias[0];
            v = fminf(v, acc[mt][1][reg] + bias[1]);
            v = fminf(v, acc[mt][2][reg] + bias[2]);
            v = fminf(v, acc[mt][3][reg] + bias[3]);
            v = fminf(v, __shfl_xor(v, 1));
            v = fminf(v, __shfl_xor(v, 2));
            v = fminf(v, __shfl_xor(v, 4));
            v = fminf(v, __shfl_xor(v, 8));
            mv[reg] = v;
        }
        const int r2 = lane & 3;
        float v = mv[0];
        v = (r2 == 1) ? mv[1] : v;
        v = (r2 == 2) ? mv[2] : v;
        v = (r2 == 3) ? mv[3] : v;
        v = tanhf(tanhf(v));
        if (m15 < 4) {
            const int pix = q * 4 + r2;
            const int gh  = h0 + wave * 4 + mt;
            const int gw  = w0 + pix;
            out[((size_t)n * 256 + gh) * 256 + gw] = v;
        }
    }
}

extern "C" void kernel_launch(void* const* d_in, const int* in_sizes, int n_in,
                              void* d_out, int out_size, void* d_ws, size_t ws_size,
                              hipStream_t stream) {
    const float* x = (const float*)d_in[0];
    const float* w = (const float*)d_in[1];
    const float* b = (const float*)d_in[2];
    float* out = (float*)d_out;
    __bf16* wB = (__bf16*)d_ws;
    __bf16* xP = (__bf16*)((char*)d_ws + WB_BYTES);  // ws_size >= WS_NEEDED verified in r3

    conv_prep_w<<<dim3(144), dim3(256), 0, stream>>>(w, wB);
    conv_zero_border<<<dim3(16, 4), dim3(256), 0, stream>>>(xP);
    conv_prep_x<<<dim3(4, 256, 16), dim3(256), 0, stream>>>(x, xP);
    conv_min_tanh_main<<<dim3(16, 16, 16), dim3(256), 0, stream>>>(xP, wB, b, out);
}

// Round 5
// 472.807 us; speedup vs baseline: 4.2777x; 1.0173x over previous
//
#include <hip/hip_runtime.h>
#include <hip/hip_bf16.h>
#include <math.h>

// Fused conv3x3(64->64) + bias + min_k + tanh(tanh()) via bf16 MFMA implicit GEMM.
// x: [16,64,256,256] f32, w: [64,64,3,3] f32, b: [64] f32, out: [16,1,256,256] f32
//
// Round 5: prep_x LDS transpose -> pure REGISTER transpose (no LDS, no conflicts).
//   xP layout: [n][hp(258)][cg(8)][wp(258)][cl(8)] bf16  (c = cg*8+cl).
//   prep_x thread: read float4 (4 px) from each of 8 channel planes (coalesced),
//   repack in regs, write 4 contiguous bf16x8 (64 B/thread, wave-contiguous).
//   main: A-frag = 16B at ((n*258+hp)*8+cg)*258*8 + wp*8, cg = chunk*4+q. B in LDS.
// mfma_f32_16x16x32_bf16: A[m=lane&15][k=(lane>>4)*8+j], B[k=(lane>>4)*8+j][n=lane&15],
//                         C/D col=lane&15, row=(lane>>4)*4+reg (HW-verified r2-r4).

typedef __bf16 bf16x8 __attribute__((ext_vector_type(8)));
typedef float f32x4 __attribute__((ext_vector_type(4)));

#define WB_ELEMS (64 * 64 * 9)
#define WB_BYTES (WB_ELEMS * 2)                    // 73728
#define XP_BYTES (16ull * 258 * 8 * 258 * 8 * 2)   // 136323072
#define HPSTRIDE ((size_t)(8 * 258 * 8))           // elements per hp step = 16512

// ---- weight prep: w[k][c][tap] -> wB[(((chunk*9+tap)*4+nt)*64+lane)*8+j] ----
__global__ __launch_bounds__(256)
void conv_prep_w(const float* __restrict__ w, __bf16* __restrict__ wB) {
    int idx = blockIdx.x * 256 + threadIdx.x;
    if (idx >= WB_ELEMS) return;
    int k   = idx / 576;
    int rem = idx - k * 576;
    int c   = rem / 9;
    int tap = rem - c * 9;
    int nt = k >> 4, m15 = k & 15;
    int chunk = c >> 5, q = (c >> 3) & 3, j = c & 7;
    int lane = (q << 4) | m15;
    wB[((((chunk * 9 + tap) * 4 + nt) * 64 + lane) << 3) + j] = (__bf16)w[idx];
}

// ---- zero the 1-pixel border of xP ----
__global__ __launch_bounds__(256)
void conv_zero_border(__bf16* __restrict__ xP) {
    const int n = blockIdx.x, seg = blockIdx.y;
    const bf16x8 z = (bf16x8)(__bf16)0.f;
    for (int i = threadIdx.x; i < 258 * 8; i += 256) {
        int hp, cg, wp;
        if (seg < 2) { hp = seg ? 257 : 0; cg = i / 258; wp = i - cg * 258; }
        else         { hp = i >> 3; cg = i & 7; wp = (seg == 2) ? 0 : 257; }
        *(bf16x8*)&xP[(((size_t)(n * 258 + hp) * 8 + cg) * 258 + wp) * 8] = z;
    }
}

// ---- x prep: register transpose. Block = 128 px x 64 c for one (n, hp). ----
__global__ __launch_bounds__(256)
void conv_prep_x(const float* __restrict__ x, __bf16* __restrict__ xP) {
    const int tid = threadIdx.x;
    const int cg  = tid >> 5;                 // 0..7
    const int t   = tid & 31;                 // 0..31 -> 4 px each
    const int n   = blockIdx.z;
    const int hp  = blockIdx.y + 1;           // padded row 1..256
    const int wbase = blockIdx.x * 128;       // input cols wbase..wbase+127

    const float* src = x + (size_t)n * 64 * 65536 + (size_t)cg * 8 * 65536
                         + (size_t)(hp - 1) * 256 + wbase + t * 4;
    float4 v[8];
#pragma unroll
    for (int j = 0; j < 8; ++j)
        v[j] = *(const float4*)&src[(size_t)j * 65536];

    __bf16* dst = xP + (((size_t)(n * 258 + hp) * 8 + cg) * 258 + (1 + wbase + t * 4)) * 8;
#pragma unroll
    for (int i = 0; i < 4; ++i) {
        bf16x8 o;
        o[0] = (__bf16)v[0][i]; o[1] = (__bf16)v[1][i];
        o[2] = (__bf16)v[2][i]; o[3] = (__bf16)v[3][i];
        o[4] = (__bf16)v[4][i]; o[5] = (__bf16)v[5][i];
        o[6] = (__bf16)v[6][i]; o[7] = (__bf16)v[7][i];
        *(bf16x8*)&dst[i * 8] = o;
    }
}

// ---- main: B in LDS, A in regs, MFMA stream ----
__global__ __launch_bounds__(256, 2)
void conv_min_tanh_main(const __bf16* __restrict__ xP,
                        const __bf16* __restrict__ wB,
                        const float* __restrict__ b,
                        float* __restrict__ out)
{
    __shared__ __attribute__((aligned(16))) __bf16 sB[9 * 4 * 64 * 8];  // 36 KB, one chunk

    const int tid  = threadIdx.x;
    const int lane = tid & 63;
    const int wave = tid >> 6;
    const int n    = blockIdx.z;
    const int h0   = blockIdx.y * 16;
    const int w0   = blockIdx.x * 16;
    const int m15  = lane & 15;
    const int q    = lane >> 4;

    f32x4 acc[4][4];  // [mt][nt]
#pragma unroll
    for (int mt = 0; mt < 4; ++mt)
#pragma unroll
        for (int nt = 0; nt < 4; ++nt)
            acc[mt][nt] = (f32x4){0.f, 0.f, 0.f, 0.f};

    // lane A base: hp = h0+4*wave, cg = q (chunk 0), wp = w0+m15, cl = 0
    const __bf16* xbase = xP + (((size_t)(n * 258 + h0 + 4 * wave) * 8 + q) * 258
                                + (w0 + m15)) * 8;

#pragma unroll 1
    for (int chunk = 0; chunk < 2; ++chunk) {
        if (chunk) __syncthreads();          // all reads of sB chunk 0 done
        {   // stage this chunk's 36 KB of B into LDS (contiguous copy)
            const float4* src = (const float4*)(wB + chunk * (9 * 4 * 64 * 8));
            float4* dst = (float4*)sB;
#pragma unroll
            for (int i = 0; i < 9; ++i)
                dst[i * 256 + tid] = src[i * 256 + tid];
        }
        __syncthreads();

        // burst-load the 18 A fragments for this chunk: rows 0..5, s 0..2
        bf16x8 af[6][3];
        const __bf16* xc = xbase + (size_t)chunk * 4 * 258 * 8;   // cg += 4
#pragma unroll
        for (int row = 0; row < 6; ++row)
#pragma unroll
            for (int s = 0; s < 3; ++s)
                af[row][s] = *(const bf16x8*)&xc[(size_t)row * HPSTRIDE + s * 8];

#pragma unroll
        for (int r = 0; r < 3; ++r) {
#pragma unroll
            for (int s = 0; s < 3; ++s) {
                const int tap = r * 3 + s;
                bf16x8 bf[4];
#pragma unroll
                for (int nt = 0; nt < 4; ++nt)
                    bf[nt] = *(const bf16x8*)&sB[((tap * 4 + nt) * 64 + lane) << 3];
#pragma unroll
                for (int mt = 0; mt < 4; ++mt)
#pragma unroll
                    for (int nt = 0; nt < 4; ++nt)
                        acc[mt][nt] = __builtin_amdgcn_mfma_f32_16x16x32_bf16(
                            af[mt + r][s], bf[nt], acc[mt][nt], 0, 0, 0);
            }
        }
    }

    // ---- epilogue: +bias, min over 64 k, tanh(tanh), store (verified r2-r4) ----
    float bias[4];
#pragma unroll
    for (int nt = 0; nt < 4; ++nt) bias[nt] = b[nt * 16 + m15];

#pragma unroll
    for (int mt = 0; mt < 4; ++mt) {
        float mv[4];
#pragma unroll
        for (int reg = 0; reg < 4; ++reg) {
            float v = acc[mt][0][reg] + bias[0];
            v = fminf(v, acc[mt][1][reg] + bias[1]);
            v = fminf(v, acc[mt][2][reg] + bias[2]);
            v = fminf(v, acc[mt][3][reg] + bias[3]);
            v = fminf(v, __shfl_xor(v, 1));
            v = fminf(v, __shfl_xor(v, 2));
            v = fminf(v, __shfl_xor(v, 4));
            v = fminf(v, __shfl_xor(v, 8));
            mv[reg] = v;
        }
        const int r2 = lane & 3;
        float v = mv[0];
        v = (r2 == 1) ? mv[1] : v;
        v = (r2 == 2) ? mv[2] : v;
        v = (r2 == 3) ? mv[3] : v;
        v = tanhf(tanhf(v));
        if (m15 < 4) {
            const int pix = q * 4 + r2;
            const int gh  = h0 + wave * 4 + mt;
            const int gw  = w0 + pix;
            out[((size_t)n * 256 + gh) * 256 + gw] = v;
        }
    }
}

extern "C" void kernel_launch(void* const* d_in, const int* in_sizes, int n_in,
                              void* d_out, int out_size, void* d_ws, size_t ws_size,
                              hipStream_t stream) {
    const float* x = (const float*)d_in[0];
    const float* w = (const float*)d_in[1];
    const float* b = (const float*)d_in[2];
    float* out = (float*)d_out;
    __bf16* wB = (__bf16*)d_ws;
    __bf16* xP = (__bf16*)((char*)d_ws + WB_BYTES);

    conv_prep_w<<<dim3(144), dim3(256), 0, stream>>>(w, wB);
    conv_zero_border<<<dim3(16, 4), dim3(256), 0, stream>>>(xP);
    conv_prep_x<<<dim3(2, 256, 16), dim3(256), 0, stream>>>(x, xP);
    conv_min_tanh_main<<<dim3(16, 16, 16), dim3(256), 0, stream>>>(xP, wB, b, out);
}

// Round 6
// 439.141 us; speedup vs baseline: 4.6056x; 1.0767x over previous
//
#include <hip/hip_runtime.h>
#include <hip/hip_bf16.h>
#include <math.h>

// Fused conv3x3(64->64) + bias + min_k + tanh(tanh()) via bf16 MFMA implicit GEMM.
// x: [16,64,256,256] f32, w: [64,64,3,3] f32, b: [64] f32, out: [16,1,256,256] f32
//
// Round 6: SINGLE fused kernel (prep_x/xP eliminated).
//   Per 16x16 output tile, per c-chunk(32): stage A-halo [18 rows][20 px][40 slots]
//   bf16 into LDS via register transpose (8 coalesced float4 plane-reads per slot,
//   4 ds_write_b128). px-stride 80 B -> both staged writes and frag reads are
//   <=2-way bank aliasing (free, m136). B staged to LDS as before (36 KB/chunk).
//   Compute core + epilogue identical to r5 (verified): A-frags now ds_read_b128.
// mfma_f32_16x16x32_bf16: A[m=lane&15][k=(lane>>4)*8+j], B[k=(lane>>4)*8+j][n=lane&15],
//                         C/D col=lane&15, row=(lane>>4)*4+reg (HW-verified r2-r5).

typedef __bf16 bf16x8 __attribute__((ext_vector_type(8)));
typedef float f32x4 __attribute__((ext_vector_type(4)));

#define WB_ELEMS (64 * 64 * 9)
#define SA_PX   40                      // elements per pixel slot (32 used + 8 pad)
#define SA_ROW  (20 * SA_PX)            // 800 elements per row (20 px)

// ---- weight prep: w[k][c][tap] -> wB[(((chunk*9+tap)*4+nt)*64+lane)*8+j] ----
__global__ __launch_bounds__(256)
void conv_prep_w(const float* __restrict__ w, __bf16* __restrict__ wB) {
    int idx = blockIdx.x * 256 + threadIdx.x;
    if (idx >= WB_ELEMS) return;
    int k   = idx / 576;
    int rem = idx - k * 576;
    int c   = rem / 9;
    int tap = rem - c * 9;
    int nt = k >> 4, m15 = k & 15;
    int chunk = c >> 5, q = (c >> 3) & 3, j = c & 7;
    int lane = (q << 4) | m15;
    wB[((((chunk * 9 + tap) * 4 + nt) * 64 + lane) << 3) + j] = (__bf16)w[idx];
}

// ---- fused: stage(global fp32 -> LDS bf16, transposed) + MFMA + min/tanh epilogue ----
__global__ __launch_bounds__(256, 2)
void conv_min_tanh_fused(const float* __restrict__ x,
                         const __bf16* __restrict__ wB,
                         const float* __restrict__ b,
                         float* __restrict__ out)
{
    __shared__ __attribute__((aligned(16))) __bf16 sA[18 * SA_ROW];     // 28800 B
    __shared__ __attribute__((aligned(16))) __bf16 sB[9 * 4 * 64 * 8];  // 36864 B

    const int tid  = threadIdx.x;
    const int lane = tid & 63;
    const int wave = tid >> 6;
    const int n    = blockIdx.z;
    const int h0   = blockIdx.y * 16;
    const int w0   = blockIdx.x * 16;
    const int m15  = lane & 15;
    const int q    = lane >> 4;

    f32x4 acc[4][4];  // [mt][nt]
#pragma unroll
    for (int mt = 0; mt < 4; ++mt)
#pragma unroll
        for (int nt = 0; nt < 4; ++nt)
            acc[mt][nt] = (f32x4){0.f, 0.f, 0.f, 0.f};

#pragma unroll 1
    for (int chunk = 0; chunk < 2; ++chunk) {
        if (chunk) __syncthreads();          // all reads of chunk-0 LDS done

        // ---- stage B: 36 KB contiguous copy ----
        {
            const f32x4* src = (const f32x4*)(wB + chunk * (9 * 4 * 64 * 8));
            f32x4* dst = (f32x4*)sB;
#pragma unroll
            for (int i = 0; i < 9; ++i)
                dst[i * 256 + tid] = src[i * 256 + tid];
        }

        // ---- stage A: halo rows h0-1..h0+16, px w0-1..w0+18, c chunk*32..+32 ----
        // slot = row*20 + span*4 + cg ; each slot: 4 px (span) x 8 c (cg)
        for (int slot = tid; slot < 360; slot += 256) {
            const int row  = slot / 20;
            const int rem  = slot - row * 20;
            const int span = rem >> 2;
            const int cg   = rem & 3;
            const int gh   = h0 + row - 1;
            const int gw0  = w0 - 1 + span * 4;

            f32x4 v[8];
            if ((unsigned)gh < 256u) {
                const float* src = x + (size_t)(n * 64 + chunk * 32 + cg * 8) * 65536
                                     + (size_t)gh * 256;
                if (gw0 >= 0 && gw0 <= 252) {
#pragma unroll
                    for (int j = 0; j < 8; ++j)
                        v[j] = *(const f32x4*)&src[(size_t)j * 65536 + gw0];
                } else {
#pragma unroll
                    for (int j = 0; j < 8; ++j)
#pragma unroll
                        for (int i = 0; i < 4; ++i) {
                            const int gw = gw0 + i;
                            v[j][i] = ((unsigned)gw < 256u) ? src[(size_t)j * 65536 + gw] : 0.f;
                        }
                }
            } else {
#pragma unroll
                for (int j = 0; j < 8; ++j)
                    v[j] = (f32x4){0.f, 0.f, 0.f, 0.f};
            }
            __bf16* wp = &sA[row * SA_ROW + (span * 4) * SA_PX + cg * 8];
#pragma unroll
            for (int i = 0; i < 4; ++i) {
                bf16x8 o;
                o[0] = (__bf16)v[0][i]; o[1] = (__bf16)v[1][i];
                o[2] = (__bf16)v[2][i]; o[3] = (__bf16)v[3][i];
                o[4] = (__bf16)v[4][i]; o[5] = (__bf16)v[5][i];
                o[6] = (__bf16)v[6][i]; o[7] = (__bf16)v[7][i];
                *(bf16x8*)&wp[i * SA_PX] = o;
            }
        }
        __syncthreads();

        // ---- load the 18 A fragments: rows wave*4..+5, s 0..2, c' = q*8 ----
        bf16x8 af[6][3];
#pragma unroll
        for (int row = 0; row < 6; ++row)
#pragma unroll
            for (int s = 0; s < 3; ++s)
                af[row][s] = *(const bf16x8*)
                    &sA[(wave * 4 + row) * SA_ROW + (m15 + s) * SA_PX + q * 8];

#pragma unroll
        for (int r = 0; r < 3; ++r) {
#pragma unroll
            for (int s = 0; s < 3; ++s) {
                const int tap = r * 3 + s;
                bf16x8 bf[4];
#pragma unroll
                for (int nt = 0; nt < 4; ++nt)
                    bf[nt] = *(const bf16x8*)&sB[((tap * 4 + nt) * 64 + lane) << 3];
#pragma unroll
                for (int mt = 0; mt < 4; ++mt)
#pragma unroll
                    for (int nt = 0; nt < 4; ++nt)
                        acc[mt][nt] = __builtin_amdgcn_mfma_f32_16x16x32_bf16(
                            af[mt + r][s], bf[nt], acc[mt][nt], 0, 0, 0);
            }
        }
    }

    // ---- epilogue: +bias, min over 64 k, tanh(tanh), store (verified r2-r5) ----
    float bias[4];
#pragma unroll
    for (int nt = 0; nt < 4; ++nt) bias[nt] = b[nt * 16 + m15];

#pragma unroll
    for (int mt = 0; mt < 4; ++mt) {
        float mv[4];
#pragma unroll
        for (int reg = 0; reg < 4; ++reg) {
            float v = acc[mt][0][reg] + bias[0];
            v = fminf(v, acc[mt][1][reg] + bias[1]);
            v = fminf(v, acc[mt][2][reg] + bias[2]);
            v = fminf(v, acc[mt][3][reg] + bias[3]);
            v = fminf(v, __shfl_xor(v, 1));
            v = fminf(v, __shfl_xor(v, 2));
            v = fminf(v, __shfl_xor(v, 4));
            v = fminf(v, __shfl_xor(v, 8));
            mv[reg] = v;
        }
        const int r2 = lane & 3;
        float v = mv[0];
        v = (r2 == 1) ? mv[1] : v;
        v = (r2 == 2) ? mv[2] : v;
        v = (r2 == 3) ? mv[3] : v;
        v = tanhf(tanhf(v));
        if (m15 < 4) {
            const int pix = q * 4 + r2;
            const int gh  = h0 + wave * 4 + mt;
            const int gw  = w0 + pix;
            out[((size_t)n * 256 + gh) * 256 + gw] = v;
        }
    }
}

extern "C" void kernel_launch(void* const* d_in, const int* in_sizes, int n_in,
                              void* d_out, int out_size, void* d_ws, size_t ws_size,
                              hipStream_t stream) {
    const float* x = (const float*)d_in[0];
    const float* w = (const float*)d_in[1];
    const float* b = (const float*)d_in[2];
    float* out = (float*)d_out;
    __bf16* wB = (__bf16*)d_ws;  // 73728 B

    conv_prep_w<<<dim3(144), dim3(256), 0, stream>>>(w, wB);
    conv_min_tanh_fused<<<dim3(16, 16, 16), dim3(256), 0, stream>>>(x, wB, b, out);
}